// Round 5
// baseline (126.251 us; speedup 1.0000x reference)
//
#include <hip/hip_runtime.h>
#include <hip/hip_cooperative_groups.h>

namespace cg = cooperative_groups;

// Problem constants (match reference)
constexpr int Bb  = 4;
constexpr int C   = 64;
constexpr int H   = 128;
constexpr int Wd  = 128;
constexpr int K   = 5;
constexpr int LOC = 2;
constexpr int KK  = K * K;        // 25
constexpr int CKK = C * KK;       // 1600
constexpr int HW  = H * Wd;       // 16384
constexpr int N   = Bb * C * HW;  // 4194304 per output tensor

typedef float v4f __attribute__((ext_vector_type(4)));  // native vec for NT stores

__device__ __forceinline__ float frcp(float x) { return __builtin_amdgcn_rcpf(x); }
__device__ __forceinline__ void nt_store4(float* p, v4f v) {
    __builtin_nontemporal_store(v, reinterpret_cast<v4f*>(p));
}

// Single cooperative kernel, 256 blocks x 1024 threads (1 block/CU).
// Phase A: sparsify this block's W row into LDS.
// Phase B: this block computes 2 rows of M = max(box5x5(chansum x), K)
//          (same strip mapping as the old k_prep).
// grid.sync()
// Phase C: sparse-gather conv for plane (b,o), plane-max, write all outputs.
__global__ void __launch_bounds__(1024, 1) k_fused(
    const float* __restrict__ x, const float* __restrict__ wgt,
    float* __restrict__ M, float* __restrict__ out0,
    float* __restrict__ out1, float* __restrict__ out2) {
    __shared__ int   s_k[CKK];
    __shared__ float s_v[CKK];
    __shared__ int   s_cnt;
    __shared__ float s_wsum;
    __shared__ float S[6][Wd];
    __shared__ float s_red[16];
    __shared__ float s_rinv;

    const int tid = threadIdx.x;
    const int plane = blockIdx.x;          // b*C + o
    const int o = plane & (C - 1);
    const int b = plane >> 6;

    if (tid == 0) { s_cnt = 0; s_wsum = 0.0f; }
    __syncthreads();

    // ---- Phase A: compact nonzero taps of W row o into LDS ----
    const float* wrow = wgt + o * CKK;
    for (int k = tid; k < CKK; k += 1024) {
        float v = wrow[k];
        if (v != 0.0f) {
            int pos = atomicAdd(&s_cnt, 1);
            s_k[pos] = k;
            s_v[pos] = v;
            atomicAdd(&s_wsum, v);
        }
    }

    // ---- Phase B: M for rows [r0, r0+1] of batch bb ----
    const int bb    = blockIdx.x >> 6;
    const int strip = blockIdx.x & 63;
    const int r0 = strip * 2;
    if (tid < 192) {
        const int lr = tid >> 5;           // 0..5 -> global row r0-2+lr
        const int c0 = (tid & 31) * 4;
        const int gr = r0 - 2 + lr;
        v4f s = {0.f, 0.f, 0.f, 0.f};
        if ((unsigned)gr < (unsigned)H) {
            const float* p = x + (((size_t)bb * C) * H + gr) * Wd + c0;
#pragma unroll
            for (int c = 0; c < C; ++c)
                s += *reinterpret_cast<const v4f*>(p + (size_t)c * HW);
        }
        *reinterpret_cast<v4f*>(&S[lr][c0]) = s;
    }
    __syncthreads();
    if (tid < 256) {
        const int lr = tid >> 7;           // 0..1
        const int w  = tid & 127;
        const int gr = r0 + lr;
        float s = 0.f;
#pragma unroll
        for (int j = 0; j < K; ++j) {
            const float* row = S[lr + j];
#pragma unroll
            for (int kk = 0; kk < K; ++kk) {
                const int ww = w + kk - LOC;
                if ((unsigned)ww < (unsigned)Wd) s += row[ww];
            }
        }
        M[bb * HW + gr * Wd + w] = fmaxf(s, (float)K);
    }

    // ---- all M written; make visible grid-wide ----
    cg::this_grid().sync();

    // ---- Phase C: conv + normalize + binarize for plane (b,o) ----
    const int   n   = s_cnt;
    const float rws = frcp(1e-10f + s_wsum);

    const float* xb = x + (size_t)b * C * HW;
    float* o0 = out0 + (size_t)plane * HW;
    float* o1 = out1 + (size_t)plane * HW;
    float* o2 = out2 + (size_t)plane * HW;
    const float* Mb = M + b * HW;

    v4f t[4];
    float lmax = -INFINITY;
#pragma unroll
    for (int it = 0; it < 4; ++it) {
        const int p = it * 4096 + tid * 4;   // 4 consecutive px, same row (4|Wd)
        const int h = p >> 7, w = p & 127;
        v4f acc = {0.f, 0.f, 0.f, 0.f};
        for (int e = 0; e < n; ++e) {
            const int   k = s_k[e];
            const float v = s_v[e];
            const int c  = k / KK;
            const int r  = k - c * KK;
            const int rj = r / K;
            const int dj = rj - LOC;
            const int dk = (r - rj * K) - LOC;
            const int hh = h + dj;
            if ((unsigned)hh < (unsigned)H) {
                const float* rowp = xb + c * HW + hh * Wd;
                const int wb = w + dk;
                float x0 = ((unsigned)(wb + 0) < (unsigned)Wd) ? rowp[wb + 0] : 0.f;
                float x1 = ((unsigned)(wb + 1) < (unsigned)Wd) ? rowp[wb + 1] : 0.f;
                float x2 = ((unsigned)(wb + 2) < (unsigned)Wd) ? rowp[wb + 2] : 0.f;
                float x3 = ((unsigned)(wb + 3) < (unsigned)Wd) ? rowp[wb + 3] : 0.f;
                acc.x += v * x0; acc.y += v * x1; acc.z += v * x2; acc.w += v * x3;
            }
        }
        nt_store4(o0 + p, acc);
        const v4f Mv = *reinterpret_cast<const v4f*>(Mb + p);
        v4f tv;
        tv.x = acc.x * frcp(Mv.x) * rws;
        tv.y = acc.y * frcp(Mv.y) * rws;
        tv.z = acc.z * frcp(Mv.z) * rws;
        tv.w = acc.w * frcp(Mv.w) * rws;
        t[it] = tv;
        lmax = fmaxf(lmax, fmaxf(fmaxf(tv.x, tv.y), fmaxf(tv.z, tv.w)));
    }

    // Plane max: wave butterfly, then LDS combine across 16 waves.
#pragma unroll
    for (int m = 32; m > 0; m >>= 1) lmax = fmaxf(lmax, __shfl_xor(lmax, m, 64));
    if ((tid & 63) == 0) s_red[tid >> 6] = lmax;
    __syncthreads();
    if (tid == 0) {
        float r = s_red[0];
#pragma unroll
        for (int q = 1; q < 16; ++q) r = fmaxf(r, s_red[q]);
        s_rinv = frcp(1e-10f + r);
    }
    __syncthreads();
    const float rinv = s_rinv;

#pragma unroll
    for (int it = 0; it < 4; ++it) {
        const int p = it * 4096 + tid * 4;
        const v4f tv = t[it];
        v4f xn, bn;
        xn = tv * rinv;
        bn.x = (xn.x * xn.x * xn.x >= 0.5f) ? 1.f : 0.f;
        bn.y = (xn.y * xn.y * xn.y >= 0.5f) ? 1.f : 0.f;
        bn.z = (xn.z * xn.z * xn.z >= 0.5f) ? 1.f : 0.f;
        bn.w = (xn.w * xn.w * xn.w >= 0.5f) ? 1.f : 0.f;
        nt_store4(o1 + p, xn);
        nt_store4(o2 + p, bn);
    }
}

extern "C" void kernel_launch(void* const* d_in, const int* in_sizes, int n_in,
                              void* d_out, int out_size, void* d_ws, size_t ws_size,
                              hipStream_t stream) {
    const float* x   = (const float*)d_in[0];
    const float* wgt = (const float*)d_in[1];
    float* out = (float*)d_out;
    float* M   = (float*)d_ws;    // [Bb*HW]

    float* out0 = out;            // x_lateral
    float* out1 = out + N;        // xn
    float* out2 = out + 2 * N;    // x_lateral_bin

    void* args[] = {(void*)&x, (void*)&wgt, (void*)&M,
                    (void*)&out0, (void*)&out1, (void*)&out2};
    hipLaunchCooperativeKernel((const void*)k_fused, dim3(Bb * C), dim3(1024),
                               args, 0, stream);
}

// Round 6
// 92.047 us; speedup vs baseline: 1.3716x; 1.3716x over previous
//
#include <hip/hip_runtime.h>

// Problem constants (match reference)
constexpr int Bb  = 4;
constexpr int C   = 64;
constexpr int H   = 128;
constexpr int Wd  = 128;
constexpr int K   = 5;
constexpr int LOC = 2;
constexpr int KK  = K * K;        // 25
constexpr int CKK = C * KK;       // 1600
constexpr int HW  = H * Wd;       // 16384
constexpr int N   = Bb * C * HW;  // 4194304 per output tensor

typedef float v4f __attribute__((ext_vector_type(4)));  // native vec for NT stores

__device__ __forceinline__ float frcp(float x) { return __builtin_amdgcn_rcpf(x); }
__device__ __forceinline__ void nt_store4(float* p, v4f v) {
    __builtin_nontemporal_store(v, reinterpret_cast<v4f*>(p));
}

// Fused chansum + 5x5 box + clamp: M[b,h,w] = max(box5x5(sum_c x), K).
// Block = 2 output rows of one batch (256 blocks x 256 threads). Halo
// re-reads across neighboring strips are L2/L3 hits (x is 16.8 MB, L3-resident).
__global__ void __launch_bounds__(256) k_prep(const float* __restrict__ x,
                                              float* __restrict__ M) {
    __shared__ float S[6][Wd];
    const int t = threadIdx.x;
    const int b = blockIdx.x >> 6;
    const int strip = blockIdx.x & 63;
    const int r0 = strip * 2;              // output rows r0, r0+1

    // Phase 1: threads 0..191 compute S (channel sum) for 6 rows x 128 cols,
    // one v4f per thread; rows outside the image are zero (pad semantics).
    if (t < 192) {
        const int lr = t >> 5;             // 0..5 -> global row r0-2+lr
        const int c0 = (t & 31) * 4;
        const int gr = r0 - 2 + lr;
        v4f s = {0.f, 0.f, 0.f, 0.f};
        if ((unsigned)gr < (unsigned)H) {
            const float* p = x + (((size_t)b * C) * H + gr) * Wd + c0;
#pragma unroll
            for (int c = 0; c < C; ++c)
                s += *reinterpret_cast<const v4f*>(p + (size_t)c * HW);
        }
        *reinterpret_cast<v4f*>(&S[lr][c0]) = s;
    }
    __syncthreads();

    // Phase 2: each thread one output pixel (2 rows x 128 cols = 256 px).
    const int lr = t >> 7;                 // 0..1
    const int w  = t & 127;
    const int gr = r0 + lr;
    float s = 0.f;
#pragma unroll
    for (int j = 0; j < K; ++j) {
        const float* row = S[lr + j];      // global row gr + j - 2 (zeroed if OOB)
#pragma unroll
        for (int kk = 0; kk < K; ++kk) {
            const int ww = w + kk - LOC;
            if ((unsigned)ww < (unsigned)Wd) s += row[ww];
        }
    }
    M[b * HW + gr * Wd + w] = fmaxf(s, (float)K);
}

// One block per (b,o) plane, 1024 threads: sparsify + pre-decode W row into
// LDS (tap -> {plane/row offset, column delta, value}), sparse-gather conv,
// write out0, keep t in registers, in-block plane max, write out1/out2.
// Nontemporal stores keep x/M resident in L2.
__global__ void __launch_bounds__(1024) k_main(
    const float* __restrict__ x, const float* __restrict__ wgt,
    const float* __restrict__ M, float* __restrict__ out0,
    float* __restrict__ out1, float* __restrict__ out2) {
    __shared__ int   s_roff[CKK];   // c*HW + dj*Wd
    __shared__ int   s_dj[CKK];     // row delta (for bounds check)
    __shared__ int   s_dk[CKK];     // col delta
    __shared__ float s_v[CKK];
    __shared__ int   s_cnt;
    __shared__ float s_wsum;
    __shared__ float s_red[16];
    __shared__ float s_rinv;

    const int tid = threadIdx.x;
    const int plane = blockIdx.x;          // b*C + o
    const int o = plane & (C - 1);
    const int b = plane >> 6;

    if (tid == 0) { s_cnt = 0; s_wsum = 0.0f; }
    __syncthreads();

    // Phase A: compact + decode nonzero taps of W row o into LDS.
    const float* wrow = wgt + o * CKK;
    for (int k = tid; k < CKK; k += 1024) {
        float v = wrow[k];
        if (v != 0.0f) {
            int pos = atomicAdd(&s_cnt, 1);
            const int c  = k / KK;
            const int r  = k - c * KK;
            const int rj = r / K;
            const int dj = rj - LOC;
            const int dk = (r - rj * K) - LOC;
            s_roff[pos] = c * HW + dj * Wd;
            s_dj[pos]   = dj;
            s_dk[pos]   = dk;
            s_v[pos]    = v;
            atomicAdd(&s_wsum, v);
        }
    }
    __syncthreads();
    const int   n   = s_cnt;
    const float rws = frcp(1e-10f + s_wsum);

    const float* xb = x + (size_t)b * C * HW;
    float* o0 = out0 + (size_t)plane * HW;
    float* o1 = out1 + (size_t)plane * HW;
    float* o2 = out2 + (size_t)plane * HW;
    const float* Mb = M + b * HW;

    v4f t[4];
    float lmax = -INFINITY;
#pragma unroll
    for (int it = 0; it < 4; ++it) {
        const int p = it * 4096 + tid * 4;   // 4 consecutive px, same row (4|Wd)
        const int h = p >> 7, w = p & 127;
        v4f acc = {0.f, 0.f, 0.f, 0.f};
        for (int e = 0; e < n; ++e) {
            const float v  = s_v[e];
            const int   hh = h + s_dj[e];
            if ((unsigned)hh < (unsigned)H) {
                const float* rowp = xb + s_roff[e] + h * Wd;  // = xb + c*HW + hh*Wd
                const int wb = w + s_dk[e];
                float x0 = ((unsigned)(wb + 0) < (unsigned)Wd) ? rowp[wb + 0] : 0.f;
                float x1 = ((unsigned)(wb + 1) < (unsigned)Wd) ? rowp[wb + 1] : 0.f;
                float x2 = ((unsigned)(wb + 2) < (unsigned)Wd) ? rowp[wb + 2] : 0.f;
                float x3 = ((unsigned)(wb + 3) < (unsigned)Wd) ? rowp[wb + 3] : 0.f;
                acc.x += v * x0; acc.y += v * x1; acc.z += v * x2; acc.w += v * x3;
            }
        }
        nt_store4(o0 + p, acc);
        const v4f Mv = *reinterpret_cast<const v4f*>(Mb + p);
        v4f tv;
        tv.x = acc.x * frcp(Mv.x) * rws;
        tv.y = acc.y * frcp(Mv.y) * rws;
        tv.z = acc.z * frcp(Mv.z) * rws;
        tv.w = acc.w * frcp(Mv.w) * rws;
        t[it] = tv;
        lmax = fmaxf(lmax, fmaxf(fmaxf(tv.x, tv.y), fmaxf(tv.z, tv.w)));
    }

    // Plane max: wave butterfly, then LDS combine across 16 waves.
#pragma unroll
    for (int m = 32; m > 0; m >>= 1) lmax = fmaxf(lmax, __shfl_xor(lmax, m, 64));
    if ((tid & 63) == 0) s_red[tid >> 6] = lmax;
    __syncthreads();
    if (tid == 0) {
        float r = s_red[0];
#pragma unroll
        for (int q = 1; q < 16; ++q) r = fmaxf(r, s_red[q]);
        s_rinv = frcp(1e-10f + r);
    }
    __syncthreads();
    const float rinv = s_rinv;

#pragma unroll
    for (int it = 0; it < 4; ++it) {
        const int p = it * 4096 + tid * 4;
        const v4f tv = t[it];
        v4f xn, bn;
        xn = tv * rinv;
        bn.x = (xn.x * xn.x * xn.x >= 0.5f) ? 1.f : 0.f;
        bn.y = (xn.y * xn.y * xn.y >= 0.5f) ? 1.f : 0.f;
        bn.z = (xn.z * xn.z * xn.z >= 0.5f) ? 1.f : 0.f;
        bn.w = (xn.w * xn.w * xn.w >= 0.5f) ? 1.f : 0.f;
        nt_store4(o1 + p, xn);
        nt_store4(o2 + p, bn);
    }
}

extern "C" void kernel_launch(void* const* d_in, const int* in_sizes, int n_in,
                              void* d_out, int out_size, void* d_ws, size_t ws_size,
                              hipStream_t stream) {
    const float* x   = (const float*)d_in[0];
    const float* wgt = (const float*)d_in[1];
    float* out = (float*)d_out;
    float* M   = (float*)d_ws;    // [Bb*HW]

    float* out0 = out;            // x_lateral
    float* out1 = out + N;        // xn
    float* out2 = out + 2 * N;    // x_lateral_bin

    k_prep<<<Bb * 64, 256, 0, stream>>>(x, M);
    k_main<<<Bb * C, 1024, 0, stream>>>(x, wgt, M, out0, out1, out2);
}